// Round 6
// baseline (256.571 us; speedup 1.0000x reference)
//
#include <hip/hip_runtime.h>
#include <math.h>

#define BB   512
#define NN   512
#define MM   128
#define CC   1024
#define ADDR 134
#define EPSF 1e-8f

__device__ __forceinline__ float softplus_f(float x) {
    return fmaxf(x, 0.0f) + log1pf(expf(-fabsf(x)));
}

// ================= K1: fc k-part + beta, kk = (beta/||k||) * k -> out_rv =================
// grid 256, block 512. Each block computes b and b+256 (shares W_fc reads).
__global__ __launch_bounds__(512) void k1_fc(
    const float* __restrict__ co, const float* __restrict__ W_fc,
    const float* __restrict__ b_fc, float* __restrict__ kk /* = out_rv region */)
{
    __shared__ __align__(16) float s_co0[CC];
    __shared__ __align__(16) float s_co1[CC];
    __shared__ float s_part0[4 * MM];
    __shared__ float s_part1[4 * MM];
    __shared__ float s_beta[2];
    __shared__ float s_red[2][2];
    __shared__ float s_scale[2];

    const int t  = threadIdx.x;
    const int b0 = blockIdx.x;
    const int b1 = blockIdx.x + 256;

    s_co0[t]       = co[(size_t)b0 * CC + t];
    s_co0[t + 512] = co[(size_t)b0 * CC + t + 512];
    s_co1[t]       = co[(size_t)b1 * CC + t];
    s_co1[t + 512] = co[(size_t)b1 * CC + t + 512];
    __syncthreads();

    {
        const int o    = t & (MM - 1);
        const int part = t >> 7;                 // 0..3, 256 C-values each
        const float* Wp = W_fc + o;
        float a0 = 0.f, a1 = 0.f, a2 = 0.f, a3 = 0.f;
        float d0 = 0.f, d1 = 0.f, d2 = 0.f, d3 = 0.f;
        const int cc0 = part * 256;
        for (int c = cc0; c < cc0 + 256; c += 4) {
            float w0 = Wp[(size_t)(c + 0) * ADDR];
            float w1 = Wp[(size_t)(c + 1) * ADDR];
            float w2 = Wp[(size_t)(c + 2) * ADDR];
            float w3 = Wp[(size_t)(c + 3) * ADDR];
            float4 u = *(const float4*)(s_co0 + c);
            float4 v = *(const float4*)(s_co1 + c);
            a0 = fmaf(u.x, w0, a0); a1 = fmaf(u.y, w1, a1);
            a2 = fmaf(u.z, w2, a2); a3 = fmaf(u.w, w3, a3);
            d0 = fmaf(v.x, w0, d0); d1 = fmaf(v.y, w1, d1);
            d2 = fmaf(v.z, w2, d2); d3 = fmaf(v.w, w3, d3);
        }
        s_part0[part * MM + o] = (a0 + a1) + (a2 + a3);
        s_part1[part * MM + o] = (d0 + d1) + (d2 + d3);

        // beta (col 128): wave 0 -> b0, wave 1 -> b1
        const int wv = t >> 6;
        if (wv < 2) {
            const int ll = t & 63;
            const float* cosrc = wv ? s_co1 : s_co0;
            const float* We = W_fc + MM;
            float e = 0.f;
            for (int c = ll; c < CC; c += 64)
                e = fmaf(cosrc[c], We[(size_t)c * ADDR], e);
            #pragma unroll
            for (int off = 32; off >= 1; off >>= 1) e += __shfl_xor(e, off, 64);
            if (ll == 0) s_beta[wv] = e + b_fc[MM];
        }
    }
    __syncthreads();

    float k0 = 0.f, k1v = 0.f;
    if (t < MM) {
        float bias = b_fc[t];
        k0  = bias + s_part0[t] + s_part0[MM + t] + s_part0[2 * MM + t] + s_part0[3 * MM + t];
        k1v = bias + s_part1[t] + s_part1[MM + t] + s_part1[2 * MM + t] + s_part1[3 * MM + t];
        float v0 = k0 * k0, v1 = k1v * k1v;
        #pragma unroll
        for (int off = 32; off >= 1; off >>= 1) {
            v0 += __shfl_xor(v0, off, 64);
            v1 += __shfl_xor(v1, off, 64);
        }
        if ((t & 63) == 0) { s_red[0][t >> 6] = v0; s_red[1][t >> 6] = v1; }
    }
    __syncthreads();
    if (t < 2) {
        float ks = s_red[t][0] + s_red[t][1];
        s_scale[t] = softplus_f(s_beta[t]) / (sqrtf(ks) + EPSF);
    }
    __syncthreads();
    if (t < MM) {
        kk[(size_t)b0 * MM + t] = k0  * s_scale[0];
        kk[(size_t)b1 * MM + t] = k1v * s_scale[1];
    }
}

// ================= K2: beta*cosine-sim, pure stream, zero barriers =================
// grid 2048 (= 512 b x 4 tiles of 128 rows), block 256 (8 groups of 32 lanes).
// bsim -> out_w region (K3 overwrites it with final w afterwards).
__global__ __launch_bounds__(256) void k2_sim(
    const float* __restrict__ mem, const float* __restrict__ kk,
    float* __restrict__ bsim /* = out_w region */)
{
    const int bb   = blockIdx.x;
    const int b    = bb >> 2;
    const int tile = bb & 3;
    const int t = threadIdx.x;
    const int g = t >> 5;
    const int l = t & 31;
    const float4* memb = (const float4*)(mem + (size_t)b * NN * MM) + (size_t)tile * 128 * 32;
    const float4 kv = ((const float4*)(kk + (size_t)b * MM))[l];
    float* bs = bsim + (size_t)b * NN + tile * 128;

    #pragma unroll
    for (int j = 0; j < 16; j += 4) {
        float4 a0 = memb[(size_t)(g + (j + 0) * 8) * 32 + l];
        float4 a1 = memb[(size_t)(g + (j + 1) * 8) * 32 + l];
        float4 a2 = memb[(size_t)(g + (j + 2) * 8) * 32 + l];
        float4 a3 = memb[(size_t)(g + (j + 3) * 8) * 32 + l];

        float d0 = a0.x*kv.x + a0.y*kv.y + a0.z*kv.z + a0.w*kv.w;
        float d1 = a1.x*kv.x + a1.y*kv.y + a1.z*kv.z + a1.w*kv.w;
        float d2 = a2.x*kv.x + a2.y*kv.y + a2.z*kv.z + a2.w*kv.w;
        float d3 = a3.x*kv.x + a3.y*kv.y + a3.z*kv.z + a3.w*kv.w;
        float q0 = a0.x*a0.x + a0.y*a0.y + a0.z*a0.z + a0.w*a0.w;
        float q1 = a1.x*a1.x + a1.y*a1.y + a1.z*a1.z + a1.w*a1.w;
        float q2 = a2.x*a2.x + a2.y*a2.y + a2.z*a2.z + a2.w*a2.w;
        float q3 = a3.x*a3.x + a3.y*a3.y + a3.z*a3.z + a3.w*a3.w;

        // fold tree: 17 shfl per 4 rows (verified rounds 3-5)
        d0 += __shfl_xor(d0, 16, 64); q0 += __shfl_xor(q0, 16, 64);
        d1 += __shfl_xor(d1, 16, 64); q1 += __shfl_xor(q1, 16, 64);
        d2 += __shfl_xor(d2, 16, 64); q2 += __shfl_xor(q2, 16, 64);
        d3 += __shfl_xor(d3, 16, 64); q3 += __shfl_xor(q3, 16, 64);
        float W0 = (l & 16) ? q0 : d0;
        float W1 = (l & 16) ? q1 : d1;
        float W2 = (l & 16) ? q2 : d2;
        float W3 = (l & 16) ? q3 : d3;
        W0 += __shfl_xor(W0, 8, 64); W1 += __shfl_xor(W1, 8, 64);
        W2 += __shfl_xor(W2, 8, 64); W3 += __shfl_xor(W3, 8, 64);
        float X0 = (l & 8) ? W1 : W0;
        float X1 = (l & 8) ? W3 : W2;
        X0 += __shfl_xor(X0, 4, 64); X1 += __shfl_xor(X1, 4, 64);
        float Y = (l & 4) ? X1 : X0;
        Y += __shfl_xor(Y, 2, 64);
        Y += __shfl_xor(Y, 1, 64);
        float Q = __shfl_xor(Y, 16, 64);
        if (l < 16 && (l & 3) == 0) {
            int jj = j + ((l & 4) >> 1) + ((l & 8) >> 3);
            bs[g + jj * 8] = Y / (sqrtf(Q) + EPSF);
        }
    }
}

// ================= K3: params recompute + softmax -> gate -> shift -> sharpen -> read_vec ===
// grid 512, block 1024. Reads bsim from out_w, kk region free; writes final outputs.
__global__ __launch_bounds__(1024) void k3_tail(
    const float* __restrict__ co, const float* __restrict__ prev_w,
    const float* __restrict__ mem, const float* __restrict__ W_fc,
    const float* __restrict__ b_fc,
    float* __restrict__ out_rv, float* __restrict__ out_w)
{
    __shared__ float s_wg[NN];
    __shared__ float s_w[NN];
    __shared__ __align__(16) float s_part[32 * MM];  // 16 KB
    __shared__ float s_scr[4 * MM];
    __shared__ float s_red[16];
    __shared__ float s_ex[16][8];
    __shared__ float s_params[8];

    const int t = threadIdx.x;
    const int b = blockIdx.x;
    const int gi = t >> 5;
    const int l  = t & 31;
    const float4* memb = (const float4*)(mem + (size_t)b * NN * MM);

    // ---- phase A: loads + fused wave-reductions (extras + softmax max) ----
    float covt = co[(size_t)b * CC + t];
    const float* We = W_fc + (size_t)t * ADDR + (MM + 1);  // cols 129..133
    float ex0 = covt * We[0];
    float ex1 = covt * We[1];
    float ex2 = covt * We[2];
    float ex3 = covt * We[3];
    float ex4 = covt * We[4];

    float pw = (t < NN) ? prev_w[(size_t)b * NN + t] : 0.0f;
    const float NEG = -3.0e38f;
    float b1 = (t < NN) ? out_w[(size_t)b * NN + t] : NEG;   // bsim staged by K2

    float m = b1;
    #pragma unroll
    for (int off = 32; off >= 1; off >>= 1) {
        m = fmaxf(m, __shfl_xor(m, off, 64));
        ex0 += __shfl_xor(ex0, off, 64);
        ex1 += __shfl_xor(ex1, off, 64);
        ex2 += __shfl_xor(ex2, off, 64);
        ex3 += __shfl_xor(ex3, off, 64);
        ex4 += __shfl_xor(ex4, off, 64);
    }
    if ((t & 63) == 0) {
        const int w = t >> 6;
        s_red[w] = m;
        s_ex[w][0] = ex0; s_ex[w][1] = ex1; s_ex[w][2] = ex2;
        s_ex[w][3] = ex3; s_ex[w][4] = ex4;
    }
    __syncthreads();

    // thread 0: finish extras -> params (while everyone computes M8)
    if (t == 0) {
        float t0 = 0.f, t1 = 0.f, t2 = 0.f, t3 = 0.f, t4 = 0.f;
        #pragma unroll
        for (int w = 0; w < 16; ++w) {
            t0 += s_ex[w][0]; t1 += s_ex[w][1]; t2 += s_ex[w][2];
            t3 += s_ex[w][3]; t4 += s_ex[w][4];
        }
        t0 += b_fc[MM + 1]; t1 += b_fc[MM + 2]; t2 += b_fc[MM + 3];
        t3 += b_fc[MM + 4]; t4 += b_fc[MM + 5];
        float g = 1.0f / (1.0f + expf(-t0));
        float mx = fmaxf(t1, fmaxf(t2, t3));
        float x0 = expf(t1 - mx), x1 = expf(t2 - mx), x2 = expf(t3 - mx);
        float inv = 1.0f / (x0 + x1 + x2);
        s_params[0] = g;
        s_params[1] = x0 * inv; s_params[2] = x1 * inv; s_params[3] = x2 * inv;
        s_params[4] = 1.0f + softplus_f(t4);
    }
    float M8 = s_red[0];
    #pragma unroll
    for (int i = 1; i < 8; ++i) M8 = fmaxf(M8, s_red[i]);
    __syncthreads();

    // softmax sum
    float e1 = (t < NN) ? expf(b1 - M8) : 0.0f;
    float ls = e1;
    #pragma unroll
    for (int off = 32; off >= 1; off >>= 1) ls += __shfl_xor(ls, off, 64);
    if ((t & 63) == 0) s_red[t >> 6] = ls;
    __syncthreads();
    float S = s_red[0];
    #pragma unroll
    for (int i = 1; i < 8; ++i) S += s_red[i];
    __syncthreads();

    // gate
    const float invS = 1.0f / S;
    const float g = s_params[0];
    float wg1 = fmaf(g, e1 * invS, (1.0f - g) * pw);
    if (t < NN) s_wg[t] = wg1;
    __syncthreads();

    // shift + sharpen (normalization deferred to outputs)
    const float sh0 = s_params[1], sh1 = s_params[2], sh2 = s_params[3];
    const float gamma = s_params[4];
    float wp1 = 0.0f;
    if (t < NN) {
        float ws1 = sh0 * s_wg[(t + NN - 1) & (NN - 1)]
                  + sh1 * wg1
                  + sh2 * s_wg[(t + 1) & (NN - 1)];
        wp1 = powf(ws1, gamma);
        s_w[t] = wp1;
    }
    __syncthreads();

    // pass 2: unnormalized read_vec (mem LLC-resident after K2), Z alongside
    float4 acc = make_float4(0.f, 0.f, 0.f, 0.f);
    for (int j = 0; j < 16; j += 4) {
        float4 a0 = memb[(size_t)(gi + (j + 0) * 32) * 32 + l];
        float4 a1 = memb[(size_t)(gi + (j + 1) * 32) * 32 + l];
        float4 a2 = memb[(size_t)(gi + (j + 2) * 32) * 32 + l];
        float4 a3 = memb[(size_t)(gi + (j + 3) * 32) * 32 + l];
        float w0 = s_w[gi + (j + 0) * 32];
        float w1 = s_w[gi + (j + 1) * 32];
        float w2 = s_w[gi + (j + 2) * 32];
        float w3 = s_w[gi + (j + 3) * 32];
        acc.x = fmaf(w0, a0.x, acc.x); acc.y = fmaf(w0, a0.y, acc.y);
        acc.z = fmaf(w0, a0.z, acc.z); acc.w = fmaf(w0, a0.w, acc.w);
        acc.x = fmaf(w1, a1.x, acc.x); acc.y = fmaf(w1, a1.y, acc.y);
        acc.z = fmaf(w1, a1.z, acc.z); acc.w = fmaf(w1, a1.w, acc.w);
        acc.x = fmaf(w2, a2.x, acc.x); acc.y = fmaf(w2, a2.y, acc.y);
        acc.z = fmaf(w2, a2.z, acc.z); acc.w = fmaf(w2, a2.w, acc.w);
        acc.x = fmaf(w3, a3.x, acc.x); acc.y = fmaf(w3, a3.y, acc.y);
        acc.z = fmaf(w3, a3.z, acc.z); acc.w = fmaf(w3, a3.w, acc.w);
    }

    float lz = wp1;
    #pragma unroll
    for (int off = 32; off >= 1; off >>= 1) lz += __shfl_xor(lz, off, 64);
    if ((t & 63) == 0) s_red[t >> 6] = lz;

    *((float4*)&s_part[gi * MM + l * 4]) = acc;
    __syncthreads();

    float Z = s_red[0];
    #pragma unroll
    for (int i = 1; i < 8; ++i) Z += s_red[i];
    const float invZ = 1.0f / (Z + EPSF);

    if (t < NN) out_w[(size_t)b * NN + t] = wp1 * invZ;   // overwrites bsim

    if (t < 512) {
        const int h = t >> 7;
        const int o = t & (MM - 1);
        float r = 0.f;
        #pragma unroll
        for (int q = 0; q < 8; ++q) r += s_part[(h * 8 + q) * MM + o];
        s_scr[h * MM + o] = r;
    }
    __syncthreads();
    if (t < MM) {
        float r = s_scr[t] + s_scr[MM + t] + s_scr[2 * MM + t] + s_scr[3 * MM + t];
        out_rv[(size_t)b * MM + t] = r * invZ;            // overwrites kk
    }
}

extern "C" void kernel_launch(void* const* d_in, const int* in_sizes, int n_in,
                              void* d_out, int out_size, void* d_ws, size_t ws_size,
                              hipStream_t stream) {
    const float* co     = (const float*)d_in[0];
    const float* prev_w = (const float*)d_in[1];
    const float* mem    = (const float*)d_in[2];
    const float* W_fc   = (const float*)d_in[3];
    const float* b_fc   = (const float*)d_in[4];
    float* out    = (float*)d_out;
    float* out_rv = out;                       // B*M floats; staged: kk, final: read_vec
    float* out_w  = out + (size_t)BB * MM;     // B*N floats; staged: bsim, final: w

    k1_fc  <<<256,  512, 0, stream>>>(co, W_fc, b_fc, out_rv);
    k2_sim <<<2048, 256, 0, stream>>>(mem, out_rv, out_w);
    k3_tail<<<512, 1024, 0, stream>>>(co, prev_w, mem, W_fc, b_fc, out_rv, out_w);
}

// Round 8
// 250.362 us; speedup vs baseline: 1.0248x; 1.0248x over previous
//
#include <hip/hip_runtime.h>
#include <math.h>

#define BB   512
#define NN   512
#define MM   128
#define CC   1024
#define ADDR 134
#define EPSF 1e-8f

__device__ __forceinline__ float softplus_f(float x) {
    return fmaxf(x, 0.0f) + log1pf(expf(-fabsf(x)));
}

// ================= K1: fc k-part + beta, kk = (beta/||k||) * k -> out_rv region ==========
// grid 256, block 512. Each block computes b and b+256 (shares W_fc reads).
__global__ __launch_bounds__(512) void k1_fc(
    const float* __restrict__ co, const float* __restrict__ W_fc,
    const float* __restrict__ b_fc, float* __restrict__ kk /* = out_rv region */)
{
    __shared__ __align__(16) float s_co0[CC];
    __shared__ __align__(16) float s_co1[CC];
    __shared__ float s_part0[4 * MM];
    __shared__ float s_part1[4 * MM];
    __shared__ float s_beta[2];
    __shared__ float s_red[2][2];
    __shared__ float s_scale[2];

    const int t  = threadIdx.x;
    const int b0 = blockIdx.x;
    const int b1 = blockIdx.x + 256;

    s_co0[t]       = co[(size_t)b0 * CC + t];
    s_co0[t + 512] = co[(size_t)b0 * CC + t + 512];
    s_co1[t]       = co[(size_t)b1 * CC + t];
    s_co1[t + 512] = co[(size_t)b1 * CC + t + 512];
    __syncthreads();

    {
        const int o    = t & (MM - 1);
        const int part = t >> 7;                 // 0..3, 256 C-values each
        const float* Wp = W_fc + o;
        float a0 = 0.f, a1 = 0.f, a2 = 0.f, a3 = 0.f;
        float d0 = 0.f, d1 = 0.f, d2 = 0.f, d3 = 0.f;
        const int cc0 = part * 256;
        for (int c = cc0; c < cc0 + 256; c += 4) {
            float w0 = Wp[(size_t)(c + 0) * ADDR];
            float w1 = Wp[(size_t)(c + 1) * ADDR];
            float w2 = Wp[(size_t)(c + 2) * ADDR];
            float w3 = Wp[(size_t)(c + 3) * ADDR];
            float4 u = *(const float4*)(s_co0 + c);
            float4 v = *(const float4*)(s_co1 + c);
            a0 = fmaf(u.x, w0, a0); a1 = fmaf(u.y, w1, a1);
            a2 = fmaf(u.z, w2, a2); a3 = fmaf(u.w, w3, a3);
            d0 = fmaf(v.x, w0, d0); d1 = fmaf(v.y, w1, d1);
            d2 = fmaf(v.z, w2, d2); d3 = fmaf(v.w, w3, d3);
        }
        s_part0[part * MM + o] = (a0 + a1) + (a2 + a3);
        s_part1[part * MM + o] = (d0 + d1) + (d2 + d3);

        // beta (col 128): wave 0 -> b0, wave 1 -> b1
        const int wv = t >> 6;
        if (wv < 2) {
            const int ll = t & 63;
            const float* cosrc = wv ? s_co1 : s_co0;
            const float* We = W_fc + MM;
            float e = 0.f;
            for (int c = ll; c < CC; c += 64)
                e = fmaf(cosrc[c], We[(size_t)c * ADDR], e);
            #pragma unroll
            for (int off = 32; off >= 1; off >>= 1) e += __shfl_xor(e, off, 64);
            if (ll == 0) s_beta[wv] = e + b_fc[MM];
        }
    }
    __syncthreads();

    float k0 = 0.f, k1v = 0.f;
    if (t < MM) {
        float bias = b_fc[t];
        k0  = bias + s_part0[t] + s_part0[MM + t] + s_part0[2 * MM + t] + s_part0[3 * MM + t];
        k1v = bias + s_part1[t] + s_part1[MM + t] + s_part1[2 * MM + t] + s_part1[3 * MM + t];
        float v0 = k0 * k0, v1 = k1v * k1v;
        #pragma unroll
        for (int off = 32; off >= 1; off >>= 1) {
            v0 += __shfl_xor(v0, off, 64);
            v1 += __shfl_xor(v1, off, 64);
        }
        if ((t & 63) == 0) { s_red[0][t >> 6] = v0; s_red[1][t >> 6] = v1; }
    }
    __syncthreads();
    if (t < 2) {
        float ks = s_red[t][0] + s_red[t][1];
        s_scale[t] = softplus_f(s_beta[t]) / (sqrtf(ks) + EPSF);
    }
    __syncthreads();
    if (t < MM) {
        kk[(size_t)b0 * MM + t] = k0  * s_scale[0];
        kk[(size_t)b1 * MM + t] = k1v * s_scale[1];
    }
}

// ================= K2: beta*cosine-sim, pure stream, zero barriers =================
// grid 2048 (= 512 b x 4 tiles of 128 rows), block 256 (8 groups of 32 lanes).
// bsim -> out_w region (k3 overwrites it with final w afterwards).
__global__ __launch_bounds__(256) void k2_sim(
    const float* __restrict__ mem, const float* __restrict__ kk,
    float* __restrict__ bsim /* = out_w region */)
{
    const int bb   = blockIdx.x;
    const int b    = bb >> 2;
    const int tile = bb & 3;
    const int t = threadIdx.x;
    const int g = t >> 5;
    const int l = t & 31;
    const float4* memb = (const float4*)(mem + (size_t)b * NN * MM) + (size_t)tile * 128 * 32;
    const float4 kv = ((const float4*)(kk + (size_t)b * MM))[l];
    float* bs = bsim + (size_t)b * NN + tile * 128;

    #pragma unroll
    for (int j = 0; j < 16; j += 4) {
        float4 a0 = memb[(size_t)(g + (j + 0) * 8) * 32 + l];
        float4 a1 = memb[(size_t)(g + (j + 1) * 8) * 32 + l];
        float4 a2 = memb[(size_t)(g + (j + 2) * 8) * 32 + l];
        float4 a3 = memb[(size_t)(g + (j + 3) * 8) * 32 + l];

        float d0 = a0.x*kv.x + a0.y*kv.y + a0.z*kv.z + a0.w*kv.w;
        float d1 = a1.x*kv.x + a1.y*kv.y + a1.z*kv.z + a1.w*kv.w;
        float d2 = a2.x*kv.x + a2.y*kv.y + a2.z*kv.z + a2.w*kv.w;
        float d3 = a3.x*kv.x + a3.y*kv.y + a3.z*kv.z + a3.w*kv.w;
        float q0 = a0.x*a0.x + a0.y*a0.y + a0.z*a0.z + a0.w*a0.w;
        float q1 = a1.x*a1.x + a1.y*a1.y + a1.z*a1.z + a1.w*a1.w;
        float q2 = a2.x*a2.x + a2.y*a2.y + a2.z*a2.z + a2.w*a2.w;
        float q3 = a3.x*a3.x + a3.y*a3.y + a3.z*a3.z + a3.w*a3.w;

        // fold tree: 17 shfl per 4 rows (verified rounds 3-6)
        d0 += __shfl_xor(d0, 16, 64); q0 += __shfl_xor(q0, 16, 64);
        d1 += __shfl_xor(d1, 16, 64); q1 += __shfl_xor(q1, 16, 64);
        d2 += __shfl_xor(d2, 16, 64); q2 += __shfl_xor(q2, 16, 64);
        d3 += __shfl_xor(d3, 16, 64); q3 += __shfl_xor(q3, 16, 64);
        float W0 = (l & 16) ? q0 : d0;
        float W1 = (l & 16) ? q1 : d1;
        float W2 = (l & 16) ? q2 : d2;
        float W3 = (l & 16) ? q3 : d3;
        W0 += __shfl_xor(W0, 8, 64); W1 += __shfl_xor(W1, 8, 64);
        W2 += __shfl_xor(W2, 8, 64); W3 += __shfl_xor(W3, 8, 64);
        float X0 = (l & 8) ? W1 : W0;
        float X1 = (l & 8) ? W3 : W2;
        X0 += __shfl_xor(X0, 4, 64); X1 += __shfl_xor(X1, 4, 64);
        float Y = (l & 4) ? X1 : X0;
        Y += __shfl_xor(Y, 2, 64);
        Y += __shfl_xor(Y, 1, 64);
        float Q = __shfl_xor(Y, 16, 64);
        if (l < 16 && (l & 3) == 0) {
            int jj = j + ((l & 4) >> 1) + ((l & 8) >> 3);
            bs[g + jj * 8] = Y / (sqrtf(Q) + EPSF);
        }
    }
}

// ================= K3: softmax -> gate -> shift -> sharpen -> final w (NO mem pass) ======
// grid 512, block 512 (8 waves). Also zeroes out_rv for k4's atomics.
__global__ __launch_bounds__(512) void k3_soft(
    const float* __restrict__ co, const float* __restrict__ prev_w,
    const float* __restrict__ W_fc, const float* __restrict__ b_fc,
    float* __restrict__ out_rv, float* __restrict__ out_w)
{
    __shared__ float s_wg[NN];
    __shared__ float s_red[8];
    __shared__ float s_ex[8][8];
    __shared__ float s_params[8];

    const int t = threadIdx.x;
    const int b = blockIdx.x;

    // params recompute: cols 129..133 of fc (each thread covers c=t and c=t+512)
    float cv0 = co[(size_t)b * CC + t];
    float cv1 = co[(size_t)b * CC + t + 512];
    const float* We0 = W_fc + (size_t)t * ADDR + (MM + 1);
    const float* We1 = W_fc + (size_t)(t + 512) * ADDR + (MM + 1);
    float ex0 = cv0 * We0[0] + cv1 * We1[0];
    float ex1 = cv0 * We0[1] + cv1 * We1[1];
    float ex2 = cv0 * We0[2] + cv1 * We1[2];
    float ex3 = cv0 * We0[3] + cv1 * We1[3];
    float ex4 = cv0 * We0[4] + cv1 * We1[4];

    float pw = prev_w[(size_t)b * NN + t];
    float b1 = out_w[(size_t)b * NN + t];        // bsim staged by k2

    // fused wave reductions: softmax max + 5 extras
    float m = b1;
    #pragma unroll
    for (int off = 32; off >= 1; off >>= 1) {
        m = fmaxf(m, __shfl_xor(m, off, 64));
        ex0 += __shfl_xor(ex0, off, 64);
        ex1 += __shfl_xor(ex1, off, 64);
        ex2 += __shfl_xor(ex2, off, 64);
        ex3 += __shfl_xor(ex3, off, 64);
        ex4 += __shfl_xor(ex4, off, 64);
    }
    if ((t & 63) == 0) {
        const int w = t >> 6;
        s_red[w] = m;
        s_ex[w][0] = ex0; s_ex[w][1] = ex1; s_ex[w][2] = ex2;
        s_ex[w][3] = ex3; s_ex[w][4] = ex4;
    }
    __syncthreads();

    if (t == 0) {
        float t0 = 0.f, t1 = 0.f, t2 = 0.f, t3 = 0.f, t4 = 0.f;
        #pragma unroll
        for (int w = 0; w < 8; ++w) {
            t0 += s_ex[w][0]; t1 += s_ex[w][1]; t2 += s_ex[w][2];
            t3 += s_ex[w][3]; t4 += s_ex[w][4];
        }
        t0 += b_fc[MM + 1]; t1 += b_fc[MM + 2]; t2 += b_fc[MM + 3];
        t3 += b_fc[MM + 4]; t4 += b_fc[MM + 5];
        float g = 1.0f / (1.0f + expf(-t0));
        float mx = fmaxf(t1, fmaxf(t2, t3));
        float x0 = expf(t1 - mx), x1 = expf(t2 - mx), x2 = expf(t3 - mx);
        float inv = 1.0f / (x0 + x1 + x2);
        s_params[0] = g;
        s_params[1] = x0 * inv; s_params[2] = x1 * inv; s_params[3] = x2 * inv;
        s_params[4] = 1.0f + softplus_f(t4);
    }
    float M8 = s_red[0];
    #pragma unroll
    for (int i = 1; i < 8; ++i) M8 = fmaxf(M8, s_red[i]);
    __syncthreads();                              // s_params visible; s_red reusable

    // softmax sum
    float e1 = expf(b1 - M8);
    float ls = e1;
    #pragma unroll
    for (int off = 32; off >= 1; off >>= 1) ls += __shfl_xor(ls, off, 64);
    if ((t & 63) == 0) s_red[t >> 6] = ls;
    __syncthreads();
    float S = s_red[0];
    #pragma unroll
    for (int i = 1; i < 8; ++i) S += s_red[i];
    __syncthreads();

    // gate
    const float invS = 1.0f / S;
    const float g = s_params[0];
    float wg1 = fmaf(g, e1 * invS, (1.0f - g) * pw);
    s_wg[t] = wg1;
    __syncthreads();

    // shift + sharpen
    const float sh0 = s_params[1], sh1 = s_params[2], sh2 = s_params[3];
    const float gamma = s_params[4];
    float ws1 = sh0 * s_wg[(t + NN - 1) & (NN - 1)]
              + sh1 * wg1
              + sh2 * s_wg[(t + 1) & (NN - 1)];
    float wp1 = powf(ws1, gamma);

    float lz = wp1;
    #pragma unroll
    for (int off = 32; off >= 1; off >>= 1) lz += __shfl_xor(lz, off, 64);
    if ((t & 63) == 0) s_red[t >> 6] = lz;
    __syncthreads();
    float Z = s_red[0];
    #pragma unroll
    for (int i = 1; i < 8; ++i) Z += s_red[i];

    out_w[(size_t)b * NN + t] = wp1 / (Z + EPSF);   // final w, overwrites bsim
    if (t < MM) out_rv[(size_t)b * MM + t] = 0.0f;  // prep for k4 atomics
}

// ================= K4: read_vec = w @ mem, pure stream + block partials + atomics =========
// grid 2048 (= 512 b x 4 tiles of 128 rows), block 256. mem is L3-resident after k2.
__global__ __launch_bounds__(256) void k4_read(
    const float* __restrict__ mem, const float* __restrict__ w,
    float* __restrict__ out_rv)
{
    __shared__ float s_w[128];
    __shared__ __align__(16) float s_part[8 * MM];

    const int bb   = blockIdx.x;
    const int b    = bb >> 2;
    const int tile = bb & 3;
    const int t = threadIdx.x;
    const int g = t >> 5;
    const int l = t & 31;
    const float4* memb = (const float4*)(mem + (size_t)b * NN * MM) + (size_t)tile * 128 * 32;

    if (t < 128) s_w[t] = w[(size_t)b * NN + tile * 128 + t];
    __syncthreads();

    float4 acc = make_float4(0.f, 0.f, 0.f, 0.f);
    #pragma unroll
    for (int jj = 0; jj < 16; ++jj) {
        const int r = g + jj * 8;
        float4 a = memb[(size_t)r * 32 + l];
        float wv = s_w[r];
        acc.x = fmaf(wv, a.x, acc.x);
        acc.y = fmaf(wv, a.y, acc.y);
        acc.z = fmaf(wv, a.z, acc.z);
        acc.w = fmaf(wv, a.w, acc.w);
    }
    *((float4*)&s_part[g * MM + l * 4]) = acc;
    __syncthreads();

    if (t < MM) {
        float r = 0.f;
        #pragma unroll
        for (int q = 0; q < 8; ++q) r += s_part[q * MM + t];
        atomicAdd(out_rv + (size_t)b * MM + t, r);
    }
}

extern "C" void kernel_launch(void* const* d_in, const int* in_sizes, int n_in,
                              void* d_out, int out_size, void* d_ws, size_t ws_size,
                              hipStream_t stream) {
    const float* co     = (const float*)d_in[0];
    const float* prev_w = (const float*)d_in[1];
    const float* mem    = (const float*)d_in[2];
    const float* W_fc   = (const float*)d_in[3];
    const float* b_fc   = (const float*)d_in[4];
    float* out    = (float*)d_out;
    float* out_rv = out;                       // staged: kk, then zeroed, final: read_vec
    float* out_w  = out + (size_t)BB * MM;     // staged: bsim, final: w

    k1_fc  <<<256,  512, 0, stream>>>(co, W_fc, b_fc, out_rv);
    k2_sim <<<2048, 256, 0, stream>>>(mem, out_rv, out_w);
    k3_soft<<<512,  512, 0, stream>>>(co, prev_w, W_fc, b_fc, out_rv, out_w);
    k4_read<<<2048, 256, 0, stream>>>(mem, out_w, out_rv);
}

// Round 9
// 227.600 us; speedup vs baseline: 1.1273x; 1.1000x over previous
//
#include <hip/hip_runtime.h>
#include <math.h>

#define BB   512
#define NN   512
#define MM   128
#define CC   1024
#define ADDR 134
#define EPSF 1e-8f

__device__ __forceinline__ float softplus_f(float x) {
    return fmaxf(x, 0.0f) + log1pf(expf(-fabsf(x)));
}

__global__ __launch_bounds__(1024, 8) void ntm_head_kernel(
    const float* __restrict__ co,      // B x C
    const float* __restrict__ prev_w,  // B x N
    const float* __restrict__ mem,     // B x N x M
    const float* __restrict__ W_fc,    // C x ADDR
    const float* __restrict__ b_fc,    // ADDR
    float* __restrict__ out_rv,        // B x M
    float* __restrict__ out_w)         // B x N
{
    __shared__ __align__(16) float s_co[CC];      // 4 KB
    __shared__ __align__(16) float s_k[MM];       // 512 B
    __shared__ float s_extra[8];
    __shared__ __align__(16) float s_bsim[NN];    // 2 KB (reused for final reduce)
    __shared__ float s_wg[NN];                    // 2 KB
    __shared__ float s_w[NN];                     // 2 KB (unnormalized wp)
    __shared__ __align__(16) float s_part[32 * MM]; // 16 KB
    __shared__ float s_red[16];
    __shared__ float s_params[8];

    const int t = threadIdx.x;
    const int b = blockIdx.x;
    const int gi = t >> 5;   // 32 groups of 32 lanes
    const int l  = t & 31;
    const float4* memb = (const float4*)(mem + (size_t)b * NN * MM);

    // ---- phase 0: stage controller_out row ----
    s_co[t] = co[(size_t)b * CC + t];
    float pw = (t < NN) ? prev_w[(size_t)b * NN + t] : 0.0f;
    __syncthreads();

    // ---- phase 1: fc (out = co @ W_fc + b_fc), 8 C-partials x 128 outputs ----
    {
        const int o    = t & (MM - 1);
        const int part = t >> 7;
        const float* Wp = W_fc + o;
        float a0 = 0.f, a1 = 0.f, a2 = 0.f, a3 = 0.f;
        const int c0 = part * (CC / 8);
        for (int c = c0; c < c0 + CC / 8; c += 4) {
            float4 cv = *(const float4*)(s_co + c);
            a0 = fmaf(cv.x, Wp[(size_t)(c + 0) * ADDR], a0);
            a1 = fmaf(cv.y, Wp[(size_t)(c + 1) * ADDR], a1);
            a2 = fmaf(cv.z, Wp[(size_t)(c + 2) * ADDR], a2);
            a3 = fmaf(cv.w, Wp[(size_t)(c + 3) * ADDR], a3);
        }
        s_part[part * MM + o] = (a0 + a1) + (a2 + a3);

        const int wv = t >> 6;
        if (wv < 6) {
            const int ll = t & 63;
            const int oe = MM + wv;
            const float* We = W_fc + oe;
            float e = 0.f;
            for (int c = ll; c < CC; c += 64)
                e = fmaf(s_co[c], We[(size_t)c * ADDR], e);
            #pragma unroll
            for (int off = 32; off >= 1; off >>= 1) e += __shfl_xor(e, off, 64);
            if (ll == 0) s_extra[wv] = e + b_fc[oe];
        }
    }
    __syncthreads();

    // ---- phase 1b: reduce fc partials, ||k||, scalar params ----
    if (t < MM) {
        float r = b_fc[t];
        #pragma unroll
        for (int p = 0; p < 8; ++p) r += s_part[p * MM + t];
        s_k[t] = r;
        float v = r * r;
        #pragma unroll
        for (int off = 32; off >= 1; off >>= 1) v += __shfl_xor(v, off, 64);
        if ((t & 63) == 0) s_red[t >> 6] = v;
    }
    __syncthreads();
    if (t == 0) {
        float ks = s_red[0] + s_red[1];
        float norm_k = sqrtf(ks) + EPSF;
        float beta = softplus_f(s_extra[0]);
        float g = 1.0f / (1.0f + __expf(-s_extra[1]));
        float e0 = s_extra[2], e1 = s_extra[3], e2 = s_extra[4];
        float mx = fmaxf(e0, fmaxf(e1, e2));
        float x0 = __expf(e0 - mx), x1 = __expf(e1 - mx), x2 = __expf(e2 - mx);
        float inv = 1.0f / (x0 + x1 + x2);
        s_params[0] = beta / norm_k;
        s_params[1] = g;
        s_params[2] = x0 * inv;
        s_params[3] = x1 * inv;
        s_params[4] = x2 * inv;
        s_params[5] = 1.0f + softplus_f(s_extra[5]);
    }
    __syncthreads();

    const float bnk = s_params[0];
    const float4 kv = ((const float4*)s_k)[l];

    // ---- pass 1: beta * cosine sim; 17-shfl fold tree per 4 rows ----
    #pragma unroll
    for (int j = 0; j < 16; j += 4) {
        float4 a0 = memb[(size_t)(gi + (j + 0) * 32) * 32 + l];
        float4 a1 = memb[(size_t)(gi + (j + 1) * 32) * 32 + l];
        float4 a2 = memb[(size_t)(gi + (j + 2) * 32) * 32 + l];
        float4 a3 = memb[(size_t)(gi + (j + 3) * 32) * 32 + l];

        float d0 = a0.x*kv.x + a0.y*kv.y + a0.z*kv.z + a0.w*kv.w;
        float q0 = a0.x*a0.x + a0.y*a0.y + a0.z*a0.z + a0.w*a0.w;
        float d1 = a1.x*kv.x + a1.y*kv.y + a1.z*kv.z + a1.w*kv.w;
        float q1 = a1.x*a1.x + a1.y*a1.y + a1.z*a1.z + a1.w*a1.w;
        float d2 = a2.x*kv.x + a2.y*kv.y + a2.z*kv.z + a2.w*kv.w;
        float q2 = a2.x*a2.x + a2.y*a2.y + a2.z*a2.z + a2.w*a2.w;
        float d3 = a3.x*kv.x + a3.y*kv.y + a3.z*kv.z + a3.w*kv.w;
        float q3 = a3.x*a3.x + a3.y*a3.y + a3.z*a3.z + a3.w*a3.w;

        // L1: fold over lane^16, pair d_i with q_i
        d0 += __shfl_xor(d0, 16, 64); q0 += __shfl_xor(q0, 16, 64);
        d1 += __shfl_xor(d1, 16, 64); q1 += __shfl_xor(q1, 16, 64);
        d2 += __shfl_xor(d2, 16, 64); q2 += __shfl_xor(q2, 16, 64);
        d3 += __shfl_xor(d3, 16, 64); q3 += __shfl_xor(q3, 16, 64);
        float W0 = (l & 16) ? q0 : d0;
        float W1 = (l & 16) ? q1 : d1;
        float W2 = (l & 16) ? q2 : d2;
        float W3 = (l & 16) ? q3 : d3;
        // L2: fold over lane^8
        W0 += __shfl_xor(W0, 8, 64); W1 += __shfl_xor(W1, 8, 64);
        W2 += __shfl_xor(W2, 8, 64); W3 += __shfl_xor(W3, 8, 64);
        float X0 = (l & 8) ? W1 : W0;
        float X1 = (l & 8) ? W3 : W2;
        // L3: fold over lane^4
        X0 += __shfl_xor(X0, 4, 64); X1 += __shfl_xor(X1, 4, 64);
        float Y = (l & 4) ? X1 : X0;
        // L4+L5
        Y += __shfl_xor(Y, 2, 64);
        Y += __shfl_xor(Y, 1, 64);
        float Q = __shfl_xor(Y, 16, 64);
        if (l < 16 && (l & 3) == 0) {
            int jj = j + ((l & 4) >> 1) + ((l & 8) >> 3);
            s_bsim[gi + jj * 32] = bnk * Y / (sqrtf(Q) + EPSF);
        }
    }
    __syncthreads();

    // ---- softmax -> gate -> shift -> sharpen (normalization deferred) ----
    float wp1 = 0.0f;
    {
        const float NEG = -3.0e38f;
        float b1 = (t < NN) ? s_bsim[t] : NEG;

        float m = b1;
        #pragma unroll
        for (int off = 32; off >= 1; off >>= 1) m = fmaxf(m, __shfl_xor(m, off, 64));
        if ((t & 63) == 0) s_red[t >> 6] = m;
        __syncthreads();
        float M8 = s_red[0];
        #pragma unroll
        for (int i = 1; i < 8; ++i) M8 = fmaxf(M8, s_red[i]);
        __syncthreads();

        float e1 = (t < NN) ? __expf(b1 - M8) : 0.0f;
        float ls = e1;
        #pragma unroll
        for (int off = 32; off >= 1; off >>= 1) ls += __shfl_xor(ls, off, 64);
        if ((t & 63) == 0) s_red[t >> 6] = ls;
        __syncthreads();
        float S = s_red[0];
        #pragma unroll
        for (int i = 1; i < 8; ++i) S += s_red[i];
        __syncthreads();

        const float invS = 1.0f / S;
        const float g = s_params[1];
        float wg1 = fmaf(g, e1 * invS, (1.0f - g) * pw);
        if (t < NN) s_wg[t] = wg1;
        __syncthreads();

        const float sh0 = s_params[2], sh1 = s_params[3], sh2 = s_params[4];
        const float gamma = s_params[5];
        if (t < NN) {
            float ws1 = sh0 * s_wg[(t + NN - 1) & (NN - 1)]
                      + sh1 * wg1
                      + sh2 * s_wg[(t + 1) & (NN - 1)];
            // ws1 > 0 always (convex combo of positive weights); fast pow
            wp1 = __expf(gamma * __logf(fmaxf(ws1, 1e-37f)));
            s_w[t] = wp1;
        }
    }

    // Z partial-reduce issued here; result consumed after the next barrier
    float lz = wp1;
    #pragma unroll
    for (int off = 32; off >= 1; off >>= 1) lz += __shfl_xor(lz, off, 64);
    if ((t & 63) == 0) s_red[t >> 6] = lz;
    __syncthreads();   // s_w + s_red visible

    // ---- pass 2: unnormalized read_vec = wp @ mem; invZ applied at outputs ----
    {
        float4 acc = make_float4(0.f, 0.f, 0.f, 0.f);
        for (int j = 0; j < 16; j += 4) {
            float4 a0 = memb[(size_t)(gi + (j + 0) * 32) * 32 + l];
            float4 a1 = memb[(size_t)(gi + (j + 1) * 32) * 32 + l];
            float4 a2 = memb[(size_t)(gi + (j + 2) * 32) * 32 + l];
            float4 a3 = memb[(size_t)(gi + (j + 3) * 32) * 32 + l];
            float w0 = s_w[gi + (j + 0) * 32];
            float w1 = s_w[gi + (j + 1) * 32];
            float w2 = s_w[gi + (j + 2) * 32];
            float w3 = s_w[gi + (j + 3) * 32];
            acc.x = fmaf(w0, a0.x, acc.x); acc.y = fmaf(w0, a0.y, acc.y);
            acc.z = fmaf(w0, a0.z, acc.z); acc.w = fmaf(w0, a0.w, acc.w);
            acc.x = fmaf(w1, a1.x, acc.x); acc.y = fmaf(w1, a1.y, acc.y);
            acc.z = fmaf(w1, a1.z, acc.z); acc.w = fmaf(w1, a1.w, acc.w);
            acc.x = fmaf(w2, a2.x, acc.x); acc.y = fmaf(w2, a2.y, acc.y);
            acc.z = fmaf(w2, a2.z, acc.z); acc.w = fmaf(w2, a2.w, acc.w);
            acc.x = fmaf(w3, a3.x, acc.x); acc.y = fmaf(w3, a3.y, acc.y);
            acc.z = fmaf(w3, a3.z, acc.z); acc.w = fmaf(w3, a3.w, acc.w);
        }
        *((float4*)&s_part[gi * MM + l * 4]) = acc;

        float Z = s_red[0];
        #pragma unroll
        for (int i = 1; i < 8; ++i) Z += s_red[i];
        const float invZ = 1.0f / (Z + EPSF);

        if (t < NN) out_w[(size_t)b * NN + t] = wp1 * invZ;
        __syncthreads();

        if (t < 512) {
            const int h = t >> 7;
            const int o = t & (MM - 1);
            float r = 0.f;
            #pragma unroll
            for (int q = 0; q < 8; ++q) r += s_part[(h * 8 + q) * MM + o];
            s_bsim[h * MM + o] = r;   // s_bsim reused as scratch
        }
        __syncthreads();
        if (t < MM) {
            float r = s_bsim[t] + s_bsim[MM + t] + s_bsim[2 * MM + t] + s_bsim[3 * MM + t];
            out_rv[(size_t)b * MM + t] = r * invZ;
        }
    }
}

extern "C" void kernel_launch(void* const* d_in, const int* in_sizes, int n_in,
                              void* d_out, int out_size, void* d_ws, size_t ws_size,
                              hipStream_t stream) {
    const float* co     = (const float*)d_in[0];
    const float* prev_w = (const float*)d_in[1];
    const float* mem    = (const float*)d_in[2];
    const float* W_fc   = (const float*)d_in[3];
    const float* b_fc   = (const float*)d_in[4];
    float* out = (float*)d_out;
    ntm_head_kernel<<<BB, 1024, 0, stream>>>(co, prev_w, mem, W_fc, b_fc,
                                             out, out + (size_t)BB * MM);
}